// Round 8
// baseline (411.448 us; speedup 1.0000x reference)
//
#include <hip/hip_runtime.h>
#include <stdint.h>

#define PR1 73856093u
#define PR2 19349663u
#define PR3 83492791u
#define PR4 2654435761u
#define PPT 8       // points per lane per round in k_scatter
#define BBITS 13    // bucket-id bits for ballot match (NB <= 8192)
#define SMALLB 16   // seps held in SGPRs when B <= SMALLB

// Branch-free uniform-divisor mod (exact for h < 2^32 via double).
__device__ __forceinline__ uint32_t fastmod(uint32_t h, uint32_t d, double inv) {
    uint32_t q = (uint32_t)((double)h * inv);
    int32_t r = (int32_t)(h - q * d);
    if (r >= (int32_t)d) r -= d;
    if (r < 0) r += d;
    return (uint32_t)r;
}

// blockIdx -> chunk swizzle: contiguous chunk runs per XCD so rank-adjacent
// output lines are RMW-merged within one XCD's L2. Any bijection is correct.
__device__ __forceinline__ int chunk_of(int bi, int C) {
    return ((C & 7) == 0) ? ((bi & 7) * (C >> 3) + (bi >> 3)) : bi;
}

// Voxel hash -> bucket id. Recomputed in k_scatter (bitwise-identical).
__device__ __forceinline__ uint32_t bucket_of(float x, float y, float z,
                                              uint32_t bid, uint32_t hop,
                                              uint32_t NBu, double invNB) {
    const uint32_t vx = (uint32_t)(int32_t)floorf(x);
    const uint32_t vy = (uint32_t)(int32_t)floorf(y);
    const uint32_t vz = (uint32_t)(int32_t)floorf(z);
    uint32_t h = vx * PR1 ^ vy * PR2 ^ vz * PR3 ^ (bid * PR4);
    h += hop;
    return fastmod(h, NBu, invNB);
}

// K1: bucket per point (float out, required output), per-chunk histogram
// (u16) -> ch[c][b]. R4's measured-best config: 256 threads, unpacked NB-int
// LDS hist, float4 loads (lane owns 4 consecutive points), SGPR seps.
__global__ __launch_bounds__(256)
void k_bucket_hist(const float* __restrict__ coords,
                   const int* __restrict__ seps, int B,
                   const int* __restrict__ hash_op_p,
                   int N, int NB, int C, int chunk, double invNB,
                   float* __restrict__ out_bucket,
                   uint16_t* __restrict__ ch) {
    extern __shared__ int hist[];          // NB ints
    __shared__ int s_seps[1024];
    const int tid = threadIdx.x;
    for (int i = tid; i < NB; i += blockDim.x) hist[i] = 0;
    const bool smallB = (B <= SMALLB);
    int sv[SMALLB];
    if (smallB) {
        #pragma unroll
        for (int j = 0; j < SMALLB; j++) sv[j] = (j < B) ? seps[j] : 0x7fffffff;
    } else {
        const int Bc = B < 1024 ? B : 1024;
        for (int j = tid; j < Bc; j += blockDim.x) s_seps[j] = seps[j];
    }
    __syncthreads();

    const uint32_t hop = (uint32_t)hash_op_p[0];
    const uint32_t NBu = (uint32_t)NB;
    const int c = chunk_of(blockIdx.x, C);
    const int start = c * chunk;            // chunk%4==0 -> start%4==0
    const int end   = min(start + chunk, N);
    int bid = 0;                            // fallback running pointer (B>16)
    for (int i0 = start + tid * 4; i0 < end; i0 += (int)blockDim.x * 4) {
        const int navail = end - i0;        // >= 1
        float xs[4], ys[4], zs[4];
        if (navail >= 4) {
            const float4* cp = (const float4*)(coords + 3 * (size_t)i0);
            const float4 a = cp[0], b4 = cp[1], c4 = cp[2];
            xs[0] = a.x;  ys[0] = a.y;  zs[0] = a.z;
            xs[1] = a.w;  ys[1] = b4.x; zs[1] = b4.y;
            xs[2] = b4.z; ys[2] = b4.w; zs[2] = c4.x;
            xs[3] = c4.y; ys[3] = c4.z; zs[3] = c4.w;
        } else {
            #pragma unroll
            for (int p = 0; p < 4; p++) {
                const int i = i0 + p;
                if (i < end) {
                    xs[p] = coords[3 * (size_t)i + 0];
                    ys[p] = coords[3 * (size_t)i + 1];
                    zs[p] = coords[3 * (size_t)i + 2];
                } else { xs[p] = ys[p] = zs[p] = 0.f; }
            }
        }
        float bf[4];
        #pragma unroll
        for (int p = 0; p < 4; p++) {
            const int i = i0 + p;
            if (i < end) {
                int mybid;
                if (smallB) {
                    mybid = 0;
                    #pragma unroll
                    for (int j = 0; j < SMALLB; j++) mybid += (sv[j] <= i) ? 1 : 0;
                } else {
                    while (bid < B) {
                        const int svv = (bid < 1024) ? s_seps[bid] : seps[bid];
                        if (svv <= i) bid++; else break;
                    }
                    mybid = bid;
                }
                const uint32_t b = bucket_of(xs[p], ys[p], zs[p],
                                             (uint32_t)mybid, hop, NBu, invNB);
                bf[p] = (float)b;
                atomicAdd(&hist[(int)b], 1);   // no return use -> ds_add (cheap)
            } else bf[p] = 0.f;
        }
        if (navail >= 4) {
            *(float4*)(out_bucket + i0) = make_float4(bf[0], bf[1], bf[2], bf[3]);
        } else {
            for (int p = 0; p < navail; p++) out_bucket[i0 + p] = bf[p];
        }
    }
    __syncthreads();
    uint16_t* dst = ch + (size_t)c * NB;
    for (int i = tid; i < NB; i += blockDim.x) dst[i] = (uint16_t)hist[i];
}

// K2 (FUSED k2a+k2b): per bucket, ONE exclusive scan over ALL C chunks,
// stored in place CLAMPED at 512 (u16). Clamp-safety: stored = min(prefix,
// 512); prefix>=512 -> slot>=512 -> dropped, below 512 exact — same drop
// semantics as the old two-level (group+tops) scheme. Tail: counts (float)
// + fused gap-fill of slots [min(count,512),512). Sg array eliminated.
// Wave reads 64 consecutive buckets per chunk-step -> coalesced 128B lines.
__global__ void k_scan_full(uint16_t* __restrict__ ch, int C, int NB,
                            float* __restrict__ out_counts,
                            float* __restrict__ out_sc) {
    const int b = blockIdx.x * blockDim.x + threadIdx.x;
    if (b >= NB) return;
    int run = 0;
    size_t idx = (size_t)b;
    for (int c = 0; c < C; c++, idx += (size_t)NB) {
        const int v = ch[idx];
        ch[idx] = (uint16_t)(run < 512 ? run : 512);
        run += v;
    }
    out_counts[b] = (float)run;
    const int c0 = run < 512 ? run : 512;
    float* p = out_sc + ((size_t)b * 512 + c0) * 3;
    for (int j = c0; j < 512; j++) {
        p[0] = 0.f; p[1] = 0.f; p[2] = 0.f;
        p += 3;
    }
}

// K3: stable within-bucket rank (arrival order) + scatter — R4's measured-
// best structure byte-for-byte in the main loop (4-wave barrier turn loop:
// the barrier pacing keeps same-XCD blocks in lockstep -> L2 write-merge;
// measured repeatedly better than baton/no-sync variants). Only change:
// prologue reads the clamped global base from ch alone (16KB/block, was
// 47KB ch+Sg). Hash recomputed from coords (bitwise-identical, no bucket_f
// read). LDS hist init = clamped base; atomic returns stay exact below 512,
// monotone >=512 above -> identical drop semantics.
__global__ __launch_bounds__(256, 4)
void k_scatter(const float* __restrict__ coords,
               const int* __restrict__ seps, int B,
               const int* __restrict__ hash_op_p,
               const uint16_t* __restrict__ ch,
               int N, int NB, int C, int chunk, double invNB,
               float* __restrict__ out_sc) {
    extern __shared__ int hist[];          // NB running counters
    const int tid = threadIdx.x;
    const int c = chunk_of(blockIdx.x, C);
    const uint16_t* r1 = ch + (size_t)c * NB;
    for (int i = tid; i < NB; i += blockDim.x) hist[i] = (int)r1[i];
    __syncthreads();

    const bool smallB = (B <= SMALLB);
    int sv[SMALLB];
    if (smallB) {
        #pragma unroll
        for (int j = 0; j < SMALLB; j++) sv[j] = (j < B) ? seps[j] : 0x7fffffff;
    }
    const uint32_t hop = (uint32_t)hash_op_p[0];
    const uint32_t NBu = (uint32_t)NB;

    const int start = c * chunk;
    const int end   = min(start + chunk, N);
    const int len   = end > start ? end - start : 0;
    const int per_round = (int)blockDim.x * PPT;     // 2048
    const int rounds = (len + per_round - 1) / per_round;
    const int lane = tid & 63;
    const int wv   = tid >> 6;
    const int nw   = (int)blockDim.x >> 6;
    const unsigned long long ltmask = ((unsigned long long)1 << lane) - 1;
    int fb_bid = 0;                         // fallback running pointer (B>16)

    for (int rd = 0; rd < rounds; rd++) {
        const int wbase = start + rd * per_round + wv * (64 * PPT);
        int bs[PPT], leader[PPT], cntv[PPT], rnk[PPT];
        float cx[PPT], cy[PPT], cz[PPT];

        #pragma unroll
        for (int s = 0; s < PPT; s++) {
            const int i = wbase + s * 64 + lane;
            const bool v = (i < end);
            cx[s] = v ? coords[3 * (size_t)i + 0] : 0.f;
            cy[s] = v ? coords[3 * (size_t)i + 1] : 0.f;
            cz[s] = v ? coords[3 * (size_t)i + 2] : 0.f;
            if (v) {
                int mybid;
                if (smallB) {
                    mybid = 0;
                    #pragma unroll
                    for (int j = 0; j < SMALLB; j++) mybid += (sv[j] <= i) ? 1 : 0;
                } else {
                    while (fb_bid < B) {
                        if (seps[fb_bid] <= i) fb_bid++; else break;
                    }
                    mybid = fb_bid;
                }
                bs[s] = (int)bucket_of(cx[s], cy[s], cz[s],
                                       (uint32_t)mybid, hop, NBu, invNB);
            } else {
                bs[s] = NB;                // sentinel, fits BBITS
            }
        }

        // Ballot multi-split: mm = mask of lanes with identical bucket id.
        #pragma unroll
        for (int s = 0; s < PPT; s++) {
            const int b = bs[s];
            unsigned long long mm = ~0ull;
            #pragma unroll
            for (int k = 0; k < BBITS; k++) {
                const unsigned long long blt = __ballot(((b >> k) & 1) != 0);
                mm &= ((b >> k) & 1) ? blt : ~blt;
            }
            leader[s] = (int)__builtin_ctzll(mm);
            cntv[s]   = (int)__builtin_popcountll(mm);
            rnk[s]    = (int)__builtin_popcountll(mm & ltmask);
        }

        // Wave turn loop: arrival order = (round, wave, sub-batch, lane) =
        // ascending point index = reference arrival order.
        int basev[PPT];
        for (int w = 0; w < nw; w++) {
            if (wv == w) {
                #pragma unroll
                for (int s = 0; s < PPT; s++) {
                    int old = 0;
                    if (bs[s] < NB && lane == leader[s])
                        old = atomicAdd(&hist[bs[s]], cntv[s]);
                    basev[s] = __shfl(old, leader[s], 64);
                }
            }
            __syncthreads();
        }

        #pragma unroll
        for (int s = 0; s < PPT; s++) {
            if (bs[s] < NB) {
                const int r = basev[s] + rnk[s];
                if (r < 512) {
                    float* p = out_sc + ((size_t)bs[s] * 512 + r) * 3;
                    p[0] = cx[s]; p[1] = cy[s]; p[2] = cz[s];
                }
            }
        }
    }
}

extern "C" void kernel_launch(void* const* d_in, const int* in_sizes, int n_in,
                              void* d_out, int out_size, void* d_ws, size_t ws_size,
                              hipStream_t stream) {
    const float* coords  = (const float*)d_in[0];
    const int*   seps    = (const int*)d_in[1];
    const int*   hash_op = (const int*)d_in[2];

    const int N = in_sizes[0] / 3;
    const int B = in_sizes[1];
    const int pad_to = ((N + 511) / 512) * 512;
    const int NB = pad_to / 512;

    float* out        = (float*)d_out;
    float* out_counts = out + (size_t)pad_to * 3;
    float* out_bucket = out_counts + NB;

    // Workspace: ch (u16, C x NB) only — Sg eliminated by the fused scan.
    int C = 1024;
    while (C > 8) {
        if ((size_t)C * NB * 2 <= ws_size) break;
        C -= 8;
    }
    int chunk = (N + C - 1) / C;
    chunk = (chunk + 3) & ~3;              // k1 float4 path needs chunk%4==0
    uint16_t* ch = (uint16_t*)d_ws;
    const size_t lds = (size_t)NB * sizeof(int);
    const double invNB = 1.0 / (double)NB;

    k_bucket_hist<<<C, 256, lds, stream>>>(coords, seps, B, hash_op, N, NB, C,
                                           chunk, invNB, out_bucket, ch);
    k_scan_full<<<(NB + 63) / 64, 64, 0, stream>>>(ch, C, NB, out_counts, out);
    k_scatter<<<C, 256, lds, stream>>>(coords, seps, B, hash_op, ch,
                                       N, NB, C, chunk, invNB, out);
}

// Round 9
// 198.547 us; speedup vs baseline: 2.0723x; 2.0723x over previous
//
#include <hip/hip_runtime.h>
#include <stdint.h>

#define PR1 73856093u
#define PR2 19349663u
#define PR3 83492791u
#define PR4 2654435761u
#define GS  32      // chunks per scan group
#define PPT 8       // points per lane per round in k_scatter
#define BBITS 13    // bucket-id bits for ballot match (NB <= 8192)
#define SMALLB 16   // seps held in SGPRs when B <= SMALLB

// Branch-free uniform-divisor mod (exact for h < 2^32 via double).
__device__ __forceinline__ uint32_t fastmod(uint32_t h, uint32_t d, double inv) {
    uint32_t q = (uint32_t)((double)h * inv);
    int32_t r = (int32_t)(h - q * d);
    if (r >= (int32_t)d) r -= d;
    if (r < 0) r += d;
    return (uint32_t)r;
}

// blockIdx -> chunk swizzle: contiguous chunk runs per XCD so rank-adjacent
// output lines are RMW-merged within one XCD's L2. Any bijection is correct.
__device__ __forceinline__ int chunk_of(int bi, int C) {
    return ((C & 7) == 0) ? ((bi & 7) * (C >> 3) + (bi >> 3)) : bi;
}

// Voxel hash -> bucket id. Recomputed in k_scatter (bitwise-identical).
__device__ __forceinline__ uint32_t bucket_of(float x, float y, float z,
                                              uint32_t bid, uint32_t hop,
                                              uint32_t NBu, double invNB) {
    const uint32_t vx = (uint32_t)(int32_t)floorf(x);
    const uint32_t vy = (uint32_t)(int32_t)floorf(y);
    const uint32_t vz = (uint32_t)(int32_t)floorf(z);
    uint32_t h = vx * PR1 ^ vy * PR2 ^ vz * PR3 ^ (bid * PR4);
    h += hop;
    return fastmod(h, NBu, invNB);
}

// K1: bucket per point (float out, required output), per-chunk histogram
// -> ch[c][b]. ONLY change vs the 199us R4 config: PACKED u16 histogram
// (two buckets per u32 word; per-chunk per-bucket count <= chunk < 65536,
// no carry; raw counts, no clamping here). LDS 31.25->15.6KB -> 8 blocks/CU
// (thread-limited) = 32 waves/CU, was 5 blocks = 20 waves. Isolated
// occupancy experiment (R6 coupled this with C=2048 and drowned the signal).
__global__ __launch_bounds__(256)
void k_bucket_hist(const float* __restrict__ coords,
                   const int* __restrict__ seps, int B,
                   const int* __restrict__ hash_op_p,
                   int N, int NB, int C, int chunk, double invNB,
                   float* __restrict__ out_bucket,
                   uint16_t* __restrict__ ch) {
    extern __shared__ unsigned int histp[];   // (NB+1)/2 packed counters
    __shared__ int s_seps[1024];
    const int tid = threadIdx.x;
    const int half = (NB + 1) >> 1;
    for (int i = tid; i < half; i += blockDim.x) histp[i] = 0u;
    const bool smallB = (B <= SMALLB);
    int sv[SMALLB];
    if (smallB) {
        #pragma unroll
        for (int j = 0; j < SMALLB; j++) sv[j] = (j < B) ? seps[j] : 0x7fffffff;
    } else {
        const int Bc = B < 1024 ? B : 1024;
        for (int j = tid; j < Bc; j += blockDim.x) s_seps[j] = seps[j];
    }
    __syncthreads();

    const uint32_t hop = (uint32_t)hash_op_p[0];
    const uint32_t NBu = (uint32_t)NB;
    const int c = chunk_of(blockIdx.x, C);
    const int start = c * chunk;            // chunk%4==0 -> start%4==0
    const int end   = min(start + chunk, N);
    int bid = 0;                            // fallback running pointer (B>16)
    for (int i0 = start + tid * 4; i0 < end; i0 += (int)blockDim.x * 4) {
        const int navail = end - i0;        // >= 1
        float xs[4], ys[4], zs[4];
        if (navail >= 4) {
            const float4* cp = (const float4*)(coords + 3 * (size_t)i0);
            const float4 a = cp[0], b4 = cp[1], c4 = cp[2];
            xs[0] = a.x;  ys[0] = a.y;  zs[0] = a.z;
            xs[1] = a.w;  ys[1] = b4.x; zs[1] = b4.y;
            xs[2] = b4.z; ys[2] = b4.w; zs[2] = c4.x;
            xs[3] = c4.y; ys[3] = c4.z; zs[3] = c4.w;
        } else {
            #pragma unroll
            for (int p = 0; p < 4; p++) {
                const int i = i0 + p;
                if (i < end) {
                    xs[p] = coords[3 * (size_t)i + 0];
                    ys[p] = coords[3 * (size_t)i + 1];
                    zs[p] = coords[3 * (size_t)i + 2];
                } else { xs[p] = ys[p] = zs[p] = 0.f; }
            }
        }
        float bf[4];
        #pragma unroll
        for (int p = 0; p < 4; p++) {
            const int i = i0 + p;
            if (i < end) {
                int mybid;
                if (smallB) {
                    mybid = 0;
                    #pragma unroll
                    for (int j = 0; j < SMALLB; j++) mybid += (sv[j] <= i) ? 1 : 0;
                } else {
                    while (bid < B) {
                        const int svv = (bid < 1024) ? s_seps[bid] : seps[bid];
                        if (svv <= i) bid++; else break;
                    }
                    mybid = bid;
                }
                const int b = (int)bucket_of(xs[p], ys[p], zs[p],
                                             (uint32_t)mybid, hop, NBu, invNB);
                bf[p] = (float)b;
                atomicAdd(&histp[b >> 1], 1u << ((b & 1) * 16));  // no return
            } else bf[p] = 0.f;
        }
        if (navail >= 4) {
            *(float4*)(out_bucket + i0) = make_float4(bf[0], bf[1], bf[2], bf[3]);
        } else {
            for (int p = 0; p < navail; p++) out_bucket[i0 + p] = bf[p];
        }
    }
    __syncthreads();
    uint16_t* dst = ch + (size_t)c * NB;
    for (int i = tid; i < NB; i += blockDim.x)
        dst[i] = (uint16_t)((histp[i >> 1] >> ((i & 1) * 16)) & 0xffffu);
}

// K2a: per bucket, exclusive scan within each group of GS chunks, stored
// CLAMPED at 512 (u16, in place); exact group totals -> Sg[g][b] (int).
// Parallel over (bucket, group) — the G-dimension parallelism is ESSENTIAL
// (R8's fused single-pass scan: 123 waves, 1.4% occupancy, 250us).
__global__ void k_scan_group(uint16_t* __restrict__ ch, int* __restrict__ Sg,
                             int C, int NB) {
    const int b = blockIdx.x * blockDim.x + threadIdx.x;
    if (b >= NB) return;
    const int g  = blockIdx.y;
    const int c0 = g * GS;
    const int c1 = min(c0 + GS, C);
    int run = 0;
    for (int c = c0; c < c1; c++) {
        const size_t idx = (size_t)c * NB + b;
        const int v = ch[idx];
        ch[idx] = (uint16_t)(run < 512 ? run : 512);
        run += v;
    }
    Sg[(size_t)g * NB + b] = run;
}

// K2b: exclusive scan over group totals (int, exact, in place); total ->
// counts (float); fused gap-fill of unwritten slots [min(count,512),512).
__global__ void k_scan_tops(int* __restrict__ Sg, int G, int NB,
                            float* __restrict__ out_counts,
                            float* __restrict__ out_sc) {
    const int b = blockIdx.x * blockDim.x + threadIdx.x;
    if (b >= NB) return;
    int run = 0;
    for (int g = 0; g < G; g++) {
        const size_t idx = (size_t)g * NB + b;
        const int v = Sg[idx];
        Sg[idx] = run;
        run += v;
    }
    out_counts[b] = (float)run;
    const int c0 = run < 512 ? run : 512;
    float* p = out_sc + ((size_t)b * 512 + c0) * 3;
    for (int j = c0; j < 512; j++) {
        p[0] = 0.f; p[1] = 0.f; p[2] = 0.f;
        p += 3;
    }
}

// K3: stable within-bucket rank (arrival order) + scatter. R4's 199us
// measured-best structure, byte-for-byte: 4-wave barrier turn loop (barrier
// pacing keeps same-XCD blocks in lockstep -> L2 write-merge; measured
// better than baton/no-sync/split variants across R1/R5/R7), PPT=8,
// unpacked NB-int LDS counters, hash recomputed from coords.
__global__ __launch_bounds__(256, 4)
void k_scatter(const float* __restrict__ coords,
               const int* __restrict__ seps, int B,
               const int* __restrict__ hash_op_p,
               const uint16_t* __restrict__ ch,
               const int* __restrict__ Sg,
               int N, int NB, int C, int chunk, double invNB,
               float* __restrict__ out_sc) {
    extern __shared__ int hist[];          // NB running counters
    const int tid = threadIdx.x;
    const int c = chunk_of(blockIdx.x, C);
    const int g = c / GS;
    const uint16_t* r1 = ch + (size_t)c * NB;
    const int*      r2 = Sg + (size_t)g * NB;
    for (int i = tid; i < NB; i += blockDim.x) hist[i] = (int)r1[i] + r2[i];
    __syncthreads();

    const bool smallB = (B <= SMALLB);
    int sv[SMALLB];
    if (smallB) {
        #pragma unroll
        for (int j = 0; j < SMALLB; j++) sv[j] = (j < B) ? seps[j] : 0x7fffffff;
    }
    const uint32_t hop = (uint32_t)hash_op_p[0];
    const uint32_t NBu = (uint32_t)NB;

    const int start = c * chunk;
    const int end   = min(start + chunk, N);
    const int len   = end > start ? end - start : 0;
    const int per_round = (int)blockDim.x * PPT;     // 2048
    const int rounds = (len + per_round - 1) / per_round;
    const int lane = tid & 63;
    const int wv   = tid >> 6;
    const int nw   = (int)blockDim.x >> 6;
    const unsigned long long ltmask = ((unsigned long long)1 << lane) - 1;
    int fb_bid = 0;                         // fallback running pointer (B>16)

    for (int rd = 0; rd < rounds; rd++) {
        const int wbase = start + rd * per_round + wv * (64 * PPT);
        int bs[PPT], leader[PPT], cntv[PPT], rnk[PPT];
        float cx[PPT], cy[PPT], cz[PPT];

        #pragma unroll
        for (int s = 0; s < PPT; s++) {
            const int i = wbase + s * 64 + lane;
            const bool v = (i < end);
            cx[s] = v ? coords[3 * (size_t)i + 0] : 0.f;
            cy[s] = v ? coords[3 * (size_t)i + 1] : 0.f;
            cz[s] = v ? coords[3 * (size_t)i + 2] : 0.f;
            if (v) {
                int mybid;
                if (smallB) {
                    mybid = 0;
                    #pragma unroll
                    for (int j = 0; j < SMALLB; j++) mybid += (sv[j] <= i) ? 1 : 0;
                } else {
                    while (fb_bid < B) {
                        if (seps[fb_bid] <= i) fb_bid++; else break;
                    }
                    mybid = fb_bid;
                }
                bs[s] = (int)bucket_of(cx[s], cy[s], cz[s],
                                       (uint32_t)mybid, hop, NBu, invNB);
            } else {
                bs[s] = NB;                // sentinel, fits BBITS
            }
        }

        // Ballot multi-split: mm = mask of lanes with identical bucket id.
        #pragma unroll
        for (int s = 0; s < PPT; s++) {
            const int b = bs[s];
            unsigned long long mm = ~0ull;
            #pragma unroll
            for (int k = 0; k < BBITS; k++) {
                const unsigned long long blt = __ballot(((b >> k) & 1) != 0);
                mm &= ((b >> k) & 1) ? blt : ~blt;
            }
            leader[s] = (int)__builtin_ctzll(mm);
            cntv[s]   = (int)__builtin_popcountll(mm);
            rnk[s]    = (int)__builtin_popcountll(mm & ltmask);
        }

        // Wave turn loop: arrival order = (round, wave, sub-batch, lane) =
        // ascending point index = reference arrival order.
        int basev[PPT];
        for (int w = 0; w < nw; w++) {
            if (wv == w) {
                #pragma unroll
                for (int s = 0; s < PPT; s++) {
                    int old = 0;
                    if (bs[s] < NB && lane == leader[s])
                        old = atomicAdd(&hist[bs[s]], cntv[s]);
                    basev[s] = __shfl(old, leader[s], 64);
                }
            }
            __syncthreads();
        }

        #pragma unroll
        for (int s = 0; s < PPT; s++) {
            if (bs[s] < NB) {
                const int r = basev[s] + rnk[s];
                if (r < 512) {
                    float* p = out_sc + ((size_t)bs[s] * 512 + r) * 3;
                    p[0] = cx[s]; p[1] = cy[s]; p[2] = cz[s];
                }
            }
        }
    }
}

extern "C" void kernel_launch(void* const* d_in, const int* in_sizes, int n_in,
                              void* d_out, int out_size, void* d_ws, size_t ws_size,
                              hipStream_t stream) {
    const float* coords  = (const float*)d_in[0];
    const int*   seps    = (const int*)d_in[1];
    const int*   hash_op = (const int*)d_in[2];

    const int N = in_sizes[0] / 3;
    const int B = in_sizes[1];
    const int pad_to = ((N + 511) / 512) * 512;
    const int NB = pad_to / 512;

    float* out        = (float*)d_out;
    float* out_counts = out + (size_t)pad_to * 3;
    float* out_bucket = out_counts + NB;

    // Workspace: ch (u16, C x NB) then Sg (int, G x NB).
    int C = 1024;
    while (C > 8) {
        const int G_ = (C + GS - 1) / GS;
        if ((size_t)C * NB * 2 + (size_t)G_ * NB * 4 <= ws_size) break;
        C -= 8;
    }
    const int G = (C + GS - 1) / GS;
    int chunk = (N + C - 1) / C;
    chunk = (chunk + 3) & ~3;              // k1 float4 path needs chunk%4==0
    uint16_t* ch = (uint16_t*)d_ws;
    int* Sg = (int*)((char*)d_ws + (((size_t)C * NB * 2 + 15) & ~(size_t)15));
    const size_t lds1 = ((size_t)(NB + 1) / 2) * sizeof(unsigned int); // 15.6KB
    const size_t lds3 = (size_t)NB * sizeof(int);                      // 31.25KB
    const double invNB = 1.0 / (double)NB;

    k_bucket_hist<<<C, 256, lds1, stream>>>(coords, seps, B, hash_op, N, NB, C,
                                            chunk, invNB, out_bucket, ch);
    dim3 g2a((NB + 63) / 64, G);
    k_scan_group<<<g2a, 64, 0, stream>>>(ch, Sg, C, NB);
    k_scan_tops<<<(NB + 63) / 64, 64, 0, stream>>>(Sg, G, NB, out_counts, out);
    k_scatter<<<C, 256, lds3, stream>>>(coords, seps, B, hash_op, ch, Sg,
                                        N, NB, C, chunk, invNB, out);
}